// Round 1
// baseline (209.530 us; speedup 1.0000x reference)
//
#include <hip/hip_runtime.h>

#define PLANES 384
#define K 11
#define TS 96            // LDS tile row stride in floats (multiple of 32 -> banks depend only on column)
#define ROWS 74          // 5 pad + 64 + 5 pad

// One block = one (n,c) plane of 64x64. 256 threads, each computes a 4x4 output tile.
// LDS layout: tile[(gy+5)*TS + gx+8] = x[plane][gy][gx]; borders zeroed (implements padding).
__global__ __launch_bounds__(256) void smpconv_kernel(
    const float* __restrict__ x,
    const float* __restrict__ wcoord,   // (1,4,2)
    const float* __restrict__ radius,   // (1,4,1,1)
    const float* __restrict__ wts,      // (1,384,4)
    float* __restrict__ out)
{
    __shared__ __align__(16) float tile[ROWS * TS];
    __shared__ __align__(16) float skv[12 * 12];   // 11 kernel rows, stride 12 (b128-aligned)
    __shared__ int s_rowmask, s_colmask;

    const int tid = threadIdx.x;
    const int bid = blockIdx.x;          // n*384 + c
    const int c   = bid % PLANES;

    // ---- phase 0: zero LDS tile (gives us the zero halo) ----
    #pragma unroll
    for (int z = 0; z < 7; ++z) {
        int e = z * 256 + tid;
        if (e < (ROWS * TS) / 4) {
            float4 zz; zz.x = zz.y = zz.z = zz.w = 0.f;
            *(float4*)&tile[e * 4] = zz;
        }
    }
    if (tid == 0) { s_rowmask = 0; s_colmask = 0; }
    __syncthreads();

    // ---- phase 1: stage input plane + generate this channel's 11x11 kernel ----
    const float* xp = x + (size_t)bid * 4096;
    #pragma unroll
    for (int it = 0; it < 4; ++it) {
        int e = it * 256 + tid;              // float4 index 0..1023
        float4 v = ((const float4*)xp)[e];
        int gy = e >> 4;                     // 16 float4 per 64-wide row
        int gx = (e & 15) << 2;
        *(float4*)&tile[(gy + 5) * TS + gx + 8] = v;   // col group = (e&15)+2: consecutive lanes -> consecutive bank quads
    }
    if (tid < K * K) {
        // kf[c,i,j] = sum_p w[c,p] * relu(1 - (|wc0 - lin[j]| + |wc1 - lin[10-i]|)/r[p])
        int i = tid / K;
        int j = tid - i * K;
        float la = -1.f + 0.2f * (float)j;
        float lb = -1.f + 0.2f * (float)(10 - i);
        float a = 0.f;
        #pragma unroll
        for (int p = 0; p < 4; ++p) {
            float ir = 1.f / radius[p];
            float t = 1.f - (fabsf(wcoord[2*p] - la) + fabsf(wcoord[2*p+1] - lb)) * ir;
            t = fmaxf(t, 0.f);
            a = fmaf(wts[c*4 + p], t, a);
        }
        skv[i * 12 + j] = a;
        if (a != 0.f) {
            atomicOr(&s_rowmask, 1 << i);
            atomicOr(&s_colmask, 1 << j);
        }
    }
    __syncthreads();

    // wave-uniform sparsity masks (scalar branches)
    const int rowmask = __builtin_amdgcn_readfirstlane(s_rowmask);
    const int colmask = __builtin_amdgcn_readfirstlane(s_colmask);

    const int ty = tid >> 4;     // 0..15 -> output rows 4ty..4ty+3
    const int tx = tid & 15;     // 0..15 -> output cols 4tx..4tx+3

    float acc[4][4];
    #pragma unroll
    for (int o = 0; o < 4; ++o)
        #pragma unroll
        for (int xx = 0; xx < 4; ++xx) acc[o][xx] = 0.f;

    float kvs[4][12];            // rotating cache of 4 kernel rows (fully unrolled -> regs)
    #pragma unroll
    for (int s = 0; s < 4; ++s)
        #pragma unroll
        for (int j = 0; j < 12; ++j) kvs[s][j] = 0.f;

    const float* rowbase = &tile[(ty * 4) * TS + tx * 4];

    #pragma unroll
    for (int rr = 0; rr < 14; ++rr) {      // input rows 4ty+rr-5
        // rotate in kernel row rr (used by o = 0..3 at iterations rr..rr+3)
        if (rr < K) {
            if ((rowmask >> rr) & 1) {
                float4 k0 = *(const float4*)&skv[rr*12 + 0];
                float4 k1 = *(const float4*)&skv[rr*12 + 4];
                float4 k2 = *(const float4*)&skv[rr*12 + 8];
                const int s = rr & 3;
                kvs[s][0]=k0.x; kvs[s][1]=k0.y; kvs[s][2]=k0.z; kvs[s][3]=k0.w;
                kvs[s][4]=k1.x; kvs[s][5]=k1.y; kvs[s][6]=k1.z; kvs[s][7]=k1.w;
                kvs[s][8]=k2.x; kvs[s][9]=k2.y; kvs[s][10]=k2.z; kvs[s][11]=k2.w;
            }
        }
        // need bit (3-o) <=> kernel row i=rr-o exists and is nonzero
        const int need = ((rowmask << 3) >> rr) & 0xF;
        if (need) {
            const float* rp = rowbase + rr * TS;   // lds cols 4tx..4tx+19 = plane cols 4tx-8..4tx+11
            float4 q0 = *(const float4*)(rp + 0);
            float4 q1 = *(const float4*)(rp + 4);
            float4 q2 = *(const float4*)(rp + 8);
            float4 q3 = *(const float4*)(rp + 12);
            float4 q4 = *(const float4*)(rp + 16);
            float w[20];
            w[0]=q0.x;  w[1]=q0.y;  w[2]=q0.z;  w[3]=q0.w;
            w[4]=q1.x;  w[5]=q1.y;  w[6]=q1.z;  w[7]=q1.w;
            w[8]=q2.x;  w[9]=q2.y;  w[10]=q2.z; w[11]=q2.w;
            w[12]=q3.x; w[13]=q3.y; w[14]=q3.z; w[15]=q3.w;
            w[16]=q4.x; w[17]=q4.y; w[18]=q4.z; w[19]=q4.w;
            #pragma unroll
            for (int o = 0; o < 4; ++o) {
                if ((need >> (3 - o)) & 1) {
                    const int s = (rr - o) & 3;
                    #pragma unroll
                    for (int j = 0; j < K; ++j) {
                        if ((colmask >> j) & 1) {
                            const float kv = kvs[s][j];
                            // plane col = 4tx+xx+j-5 -> window index xx+j+3
                            #pragma unroll
                            for (int xx = 0; xx < 4; ++xx)
                                acc[o][xx] = fmaf(w[xx + j + 3], kv, acc[o][xx]);
                        }
                    }
                }
            }
        }
    }

    float* op = out + (size_t)bid * 4096 + (ty * 4) * 64 + tx * 4;
    #pragma unroll
    for (int o = 0; o < 4; ++o) {
        float4 v;
        v.x = acc[o][0]; v.y = acc[o][1]; v.z = acc[o][2]; v.w = acc[o][3];
        *(float4*)(op + o * 64) = v;
    }
}

extern "C" void kernel_launch(void* const* d_in, const int* in_sizes, int n_in,
                              void* d_out, int out_size, void* d_ws, size_t ws_size,
                              hipStream_t stream) {
    const float* x      = (const float*)d_in[0];
    const float* wcoord = (const float*)d_in[1];
    const float* radius = (const float*)d_in[2];
    const float* wts    = (const float*)d_in[3];
    float* out          = (float*)d_out;

    const int nplanes = 16 * PLANES;   // 6144 blocks, one 64x64 plane each
    smpconv_kernel<<<dim3(nplanes), dim3(256), 0, stream>>>(x, wcoord, radius, wts, out);
}